// Round 11
// baseline (2162.554 us; speedup 1.0000x reference)
//
#include <hip/hip_runtime.h>
#include <stdint.h>
#include <stddef.h>

// ---------------- problem constants ----------------
#define S_LEN 4096
#define C_DIM 1280
#define HIDD  128
#define DID   1536

// ---------------- helpers ----------------
__device__ __forceinline__ float wave_sum(float v){
  #pragma unroll
  for(int d=1;d<64;d<<=1) v += __shfl_xor(v,d);
  return v;
}
__device__ __forceinline__ float wave_max(float v){
  #pragma unroll
  for(int d=1;d<64;d<<=1) v = fmaxf(v,__shfl_xor(v,d));
  return v;
}

// ---------------- ws layout ----------------
// float region: iv @ f[0..127], cidp @ f[128..1407], stat @ f[1408..1409], mask @ f[4096..8191]
static constexpr size_t B_ZF  = 32768;                               // fp32 zf [s][c]; reused as af [s][c]
static constexpr size_t B_Q   = B_ZF + (size_t)S_LEN*C_DIM*4;
static constexpr size_t B_KT  = B_Q  + (size_t)S_LEN*HIDD*4;         // Kt [h][s]
static constexpr size_t B_VT  = B_KT + (size_t)S_LEN*HIDD*4;         // Vt [h][s]
static constexpr size_t B_PRE = B_VT + (size_t)S_LEN*HIDD*4;         // pre [s][h]

// =================== K1: iv = mlp(cid), cidp = proj(cid) ===================
__global__ void k_prep(const float* __restrict__ cid,
                       const float* __restrict__ mlp_w, const float* __restrict__ mlp_b,
                       const float* __restrict__ proj_w, const float* __restrict__ proj_b,
                       float* __restrict__ ws){
  __shared__ float cs[DID];
  int t = threadIdx.x;                  // 128 threads
  for (int i = t; i < DID; i += 128) cs[i] = cid[i];
  __syncthreads();
  int b = blockIdx.x;
  float acc = 0.f;
  if (b == 0){
    const float* row = mlp_w + (size_t)t*DID;
    for (int j = 0; j < DID; j++) acc += row[j]*cs[j];
    ws[t] = acc + mlp_b[t];
  } else {
    int c = (b-1)*128 + t;
    const float* row = proj_w + (size_t)c*DID;
    for (int j = 0; j < DID; j++) acc += row[j]*cs[j];
    ws[128+c] = acc + proj_b[c];
  }
}

// =================== K2: per-row LayerNorm over C -> zf[s][c] fp32 ===================
__global__ __launch_bounds__(256) void k_ln_n(const float* __restrict__ z, float* __restrict__ zf){
  __shared__ float red[4];
  int s = blockIdx.x, tid = threadIdx.x;
  float sm=0.f, sq=0.f;
  for(int c=tid;c<C_DIM;c+=256){ float v = z[(size_t)c*S_LEN+s]; sm+=v; sq+=v*v; }
  sm = wave_sum(sm);
  if((tid&63)==0) red[tid>>6]=sm;
  __syncthreads();
  float tot = red[0]+red[1]+red[2]+red[3];
  __syncthreads();
  sq = wave_sum(sq);
  if((tid&63)==0) red[tid>>6]=sq;
  __syncthreads();
  float tot2 = red[0]+red[1]+red[2]+red[3];
  float m = tot*(1.f/C_DIM);
  float var = tot2*(1.f/C_DIM) - m*m;
  float r = rsqrtf(var + 1e-5f);
  for(int c=tid;c<C_DIM;c+=256) zf[(size_t)s*C_DIM+c] = (z[(size_t)c*S_LEN+s]-m)*r;
}

// =================== K3: Q/K/V scalar GEMV; Kt/Vt stored [h][s] ===================
__global__ __launch_bounds__(128) void k_qkv_n(const float* __restrict__ zf,
     const float* __restrict__ wq, const float* __restrict__ bq,
     const float* __restrict__ wk, const float* __restrict__ bk,
     const float* __restrict__ wv, const float* __restrict__ bv,
     float* __restrict__ Q, float* __restrict__ Kt, float* __restrict__ Vt){
  __shared__ float row[C_DIM];
  int s = blockIdx.x, mat = blockIdx.y, h = threadIdx.x;
  for(int i=h;i<C_DIM;i+=128) row[i] = zf[(size_t)s*C_DIM+i];
  __syncthreads();
  const float* w = (mat==0)?wq:(mat==1)?wk:wv;
  const float* b = (mat==0)?bq:(mat==1)?bk:bv;
  const float* wr = w + (size_t)h*C_DIM;
  float acc=0.f;
  for(int c=0;c<C_DIM;c++) acc += row[c]*wr[c];
  acc += b[h];
  if(mat==0)      Q [(size_t)s*HIDD+h]  = acc;
  else if(mat==1) Kt[(size_t)h*S_LEN+s] = acc;
  else            Vt[(size_t)h*S_LEN+s] = acc;
}

// =================== K4: mask[k] = sigmoid(iv.K[k]) / 64 ===================
__global__ __launch_bounds__(256) void k_mask_n(const float* __restrict__ ws, const float* __restrict__ Kt,
                                                float* __restrict__ mask){
  __shared__ float ivs[HIDD];
  int tid=threadIdx.x;
  if(tid<HIDD) ivs[tid]=ws[tid];
  __syncthreads();
  int k = blockIdx.x*256+tid;
  float acc=0.f;
  for(int h=0;h<HIDD;h++) acc += ivs[h]*Kt[(size_t)h*S_LEN+k];
  mask[k] = (1.f/(1.f+__expf(-acc))) * (1.f/64.f);
}

// =================== K5: attention, one block per query ===================
__global__ __launch_bounds__(256) void k_attn_n(const float* __restrict__ Q, const float* __restrict__ Kt,
        const float* __restrict__ Vt, const float* __restrict__ mask, float* __restrict__ pre){
  __shared__ float qv[HIDD];
  __shared__ float plog[S_LEN];
  __shared__ float red[4];
  __shared__ float redm[4][8];
  int q = blockIdx.x, tid = threadIdx.x;
  if(tid<HIDD) qv[tid]=Q[(size_t)q*HIDD+tid];
  __syncthreads();
  float lmax=-1e30f;
  for(int i=0;i<16;i++){
    int k = tid + i*256;
    float acc=0.f;
    for(int h=0;h<HIDD;h++) acc += qv[h]*Kt[(size_t)h*S_LEN+k];
    acc *= mask[k];
    plog[k]=acc;
    lmax = fmaxf(lmax, acc);
  }
  lmax = wave_max(lmax);
  if((tid&63)==0) red[tid>>6]=lmax;
  __syncthreads();
  float M = fmaxf(fmaxf(red[0],red[1]),fmaxf(red[2],red[3]));
  __syncthreads();
  float ls=0.f;
  for(int i=0;i<16;i++){
    int k = tid+i*256;
    float p = __expf(plog[k]-M);
    plog[k]=p; ls+=p;
  }
  ls = wave_sum(ls);
  if((tid&63)==0) red[tid>>6]=ls;
  __syncthreads();
  float L = red[0]+red[1]+red[2]+red[3];
  float rL = 1.f/L;
  for(int hb=0; hb<16; hb++){
    float a[8]={0,0,0,0,0,0,0,0};
    for(int i=0;i<16;i++){
      int k=tid+i*256;
      float pv = plog[k];
      #pragma unroll
      for(int j=0;j<8;j++) a[j] += pv*Vt[(size_t)(hb*8+j)*S_LEN+k];
    }
    #pragma unroll
    for(int j=0;j<8;j++){
      float x = wave_sum(a[j]);
      if((tid&63)==0) redm[tid>>6][j]=x;
    }
    __syncthreads();
    if(tid<8) pre[(size_t)q*HIDD + hb*8 + tid] = (redm[0][tid]+redm[1][tid]+redm[2][tid]+redm[3][tid])*rL;
    __syncthreads();
  }
}

// =================== K6: wo GEMV + gate + global-LN partials ===================
__global__ __launch_bounds__(256) void k_wo_n(const float* __restrict__ pre, const float* __restrict__ wo,
       const float* __restrict__ bo, const float* __restrict__ ws,
       float* __restrict__ af, float* __restrict__ stat){
  __shared__ float pv[HIDD];
  __shared__ float attb[C_DIM];
  __shared__ float red[4];
  int q=blockIdx.x, tid=threadIdx.x;
  if(tid<HIDD) pv[tid]=pre[(size_t)q*HIDD+tid];
  __syncthreads();
  float simp=0.f;
  for(int i=0;i<5;i++){
    int c = tid+i*256;
    const float* wr = wo + (size_t)c*HIDD;
    float acc=0.f;
    for(int h=0;h<HIDD;h++) acc += pv[h]*wr[h];
    acc += bo[c];
    attb[c]=acc;
    simp += acc*ws[128+c];
  }
  simp = wave_sum(simp);
  if((tid&63)==0) red[tid>>6]=simp;
  __syncthreads();
  float sim = red[0]+red[1]+red[2]+red[3];
  float wt = 1.f/(1.f+__expf(-sim));
  float s1=0.f, s2=0.f;
  for(int i=0;i<5;i++){
    int c=tid+i*256;
    float v = attb[c] - wt*ws[128+c];
    af[(size_t)q*C_DIM+c]=v;
    s1+=v; s2+=v*v;
  }
  s1=wave_sum(s1); s2=wave_sum(s2);
  __syncthreads();
  if((tid&63)==0) red[tid>>6]=s1;
  __syncthreads();
  if(tid==0) atomicAdd(&stat[0], red[0]+red[1]+red[2]+red[3]);
  __syncthreads();
  if((tid&63)==0) red[tid>>6]=s2;
  __syncthreads();
  if(tid==0) atomicAdd(&stat[1], red[0]+red[1]+red[2]+red[3]);
}

// =================== K7: global-LN normalize; out[c][s] FP32 (reference output dtype) ===================
__global__ void k_norm_n(const float* __restrict__ af, const float* __restrict__ stat,
                         float* __restrict__ out){
  constexpr float invN = 1.f/((float)S_LEN*(float)C_DIM);
  float mean = stat[0]*invN;
  float var  = stat[1]*invN - mean*mean;
  float rstd = rsqrtf(var + 1e-5f);
  size_t idx = (size_t)blockIdx.x*blockDim.x+threadIdx.x;
  size_t stride = (size_t)gridDim.x*blockDim.x;
  size_t total = (size_t)S_LEN*C_DIM;
  for(size_t i=idx;i<total;i+=stride){
    int s = (int)(i & (size_t)(S_LEN-1));
    int c = (int)(i >> 12);
    out[i] = (af[(size_t)s*C_DIM+c]-mean)*rstd;
  }
}

// =================== launch ===================
extern "C" void kernel_launch(void* const* d_in, const int* in_sizes, int n_in,
                              void* d_out, int out_size, void* d_ws, size_t ws_size,
                              hipStream_t stream){
  (void)in_sizes; (void)n_in; (void)out_size; (void)ws_size;
  const float* z      = (const float*)d_in[0];
  const float* cid    = (const float*)d_in[1];
  const float* mlp_w  = (const float*)d_in[2];
  const float* mlp_b  = (const float*)d_in[3];
  const float* proj_w = (const float*)d_in[4];
  const float* proj_b = (const float*)d_in[5];
  const float* wq_w   = (const float*)d_in[6];
  const float* wq_b   = (const float*)d_in[7];
  const float* wk_w   = (const float*)d_in[8];
  const float* wk_b   = (const float*)d_in[9];
  const float* wv_w   = (const float*)d_in[10];
  const float* wv_b   = (const float*)d_in[11];
  const float* wo_w   = (const float*)d_in[12];
  const float* wo_b   = (const float*)d_in[13];

  char*  wsb = (char*)d_ws;
  float* wsf = (float*)d_ws;
  float* Zf   = (float*)(wsb + B_ZF);     // reused as af
  float* Q    = (float*)(wsb + B_Q);
  float* Kt   = (float*)(wsb + B_KT);
  float* Vt   = (float*)(wsb + B_VT);
  float* Pre  = (float*)(wsb + B_PRE);
  float* stat = wsf + 1408;
  float* mask = wsf + 4096;

  hipMemsetAsync(stat, 0, 8, stream);
  k_prep  <<<11, 128, 0, stream>>>(cid, mlp_w, mlp_b, proj_w, proj_b, wsf);
  k_ln_n  <<<S_LEN, 256, 0, stream>>>(z, Zf);
  k_qkv_n <<<dim3(S_LEN,3), 128, 0, stream>>>(Zf, wq_w, wq_b, wk_w, wk_b, wv_w, wv_b, Q, Kt, Vt);
  k_mask_n<<<16, 256, 0, stream>>>(wsf, Kt, mask);
  k_attn_n<<<S_LEN, 256, 0, stream>>>(Q, Kt, Vt, mask, Pre);
  k_wo_n  <<<S_LEN, 256, 0, stream>>>(Pre, wo_w, wo_b, wsf, Zf, stat);
  k_norm_n<<<2048, 256, 0, stream>>>(Zf, stat, (float*)d_out);
}